// Round 1
// baseline (517.078 us; speedup 1.0000x reference)
//
#include <hip/hip_runtime.h>
#include <math.h>

#define N_NODES 10000
#define N_EDGES 160000
#define HID 32

// h[e,k] = relu(ea[e,0]*w1[0,k] + ea[e,1]*w1[1,k] + b1[k])
__global__ __launch_bounds__(256) void k_h(const float* __restrict__ ea,
                                           const float* __restrict__ w1,
                                           const float* __restrict__ b1,
                                           float* __restrict__ h) {
    int idx = blockIdx.x * 256 + threadIdx.x;   // idx = e*32 + k
    int e = idx >> 5, k = idx & 31;
    float v = ea[2 * e] * w1[k] + ea[2 * e + 1] * w1[32 + k] + b1[k];
    h[idx] = v > 0.f ? v : 0.f;
}

// G[n, o*32+k] = sum_i x[n,i] * w2[k, i*32+o]
// 16 nodes per block; each thread owns 4 consecutive output columns j=t*4+q,
// with the w2 column (DIN values) held in registers, x broadcast from LDS.
template <int DIN, bool FIRST>
__global__ __launch_bounds__(256) void k_G(const float* __restrict__ xin,  // FIRST: x0 [N,DIN]; else agg [N,32] (relu applied)
                                           const float* __restrict__ w2,  // [32, DIN*32]
                                           float* __restrict__ G) {
    const int t = threadIdx.x;
    const int n0 = blockIdx.x * 16;

    float w2r[4][DIN];
#pragma unroll
    for (int q = 0; q < 4; ++q) {
        int j = t * 4 + q;
        int o = j >> 5, k = j & 31;
#pragma unroll
        for (int i = 0; i < DIN; ++i)
            w2r[q][i] = w2[k * (DIN * 32) + i * 32 + o];
    }

    __shared__ float xs[16 * DIN];
    for (int idx = t; idx < 16 * DIN; idx += 256) {
        int m = idx / DIN, i = idx - m * DIN;
        float v;
        if (FIRST) {
            v = xin[(size_t)(n0 + m) * DIN + i];
        } else {
            v = xin[(size_t)(n0 + m) * 32 + i];
            v = v > 0.f ? v : 0.f;
        }
        xs[idx] = v;
    }
    __syncthreads();

    for (int m = 0; m < 16; ++m) {
        float acc0 = 0.f, acc1 = 0.f, acc2 = 0.f, acc3 = 0.f;
#pragma unroll
        for (int i = 0; i < DIN; ++i) {
            float xv = xs[m * DIN + i];   // LDS broadcast (same addr all threads)
            acc0 += xv * w2r[0][i];
            acc1 += xv * w2r[1][i];
            acc2 += xv * w2r[2][i];
            acc3 += xv * w2r[3][i];
        }
        float4* dst = (float4*)(G + (size_t)(n0 + m) * 1024 + t * 4);
        *dst = make_float4(acc0, acc1, acc2, acc3);
    }
}

// xb2[n,o] = sum_i x[n,i]*b2[i*32+o];  agg[n,o] = bias[o] + sum_i x[n,i]*root[i,o]
template <int DIN, bool FIRST>
__global__ __launch_bounds__(256) void k_small(const float* __restrict__ xin,
                                               const float* __restrict__ b2,
                                               const float* __restrict__ root,
                                               const float* __restrict__ bias,
                                               float* __restrict__ xb2,
                                               float* __restrict__ aggout) {
    int t = threadIdx.x;
    int n = blockIdx.x * 8 + (t >> 5);
    int o = t & 31;
    float ab = 0.f, ar = bias[o];
#pragma unroll
    for (int i = 0; i < DIN; ++i) {
        float xv;
        if (FIRST) {
            xv = xin[(size_t)n * DIN + i];
        } else {
            xv = xin[(size_t)n * 32 + i];
            xv = xv > 0.f ? xv : 0.f;
        }
        ab += xv * b2[i * 32 + o];
        ar += xv * root[i * 32 + o];
    }
    xb2[(size_t)n * 32 + o] = ab;
    aggout[(size_t)n * 32 + o] = ar;
}

// msg[e,o] = xb2[src,o] + sum_k h[e,k]*G[src, o*32+k];  atomicAdd into agg[dst,o]
__global__ __launch_bounds__(256) void k_edge(const int* __restrict__ ei,
                                              const float* __restrict__ h,
                                              const float* __restrict__ G,
                                              const float* __restrict__ xb2,
                                              float* __restrict__ aggout) {
    __shared__ float hs[256];
    __shared__ int ss[8], ds[8];
    int t = threadIdx.x;
    int e0 = blockIdx.x * 8;
    hs[t] = h[(size_t)e0 * 32 + t];
    if (t < 8) ss[t] = ei[e0 + t];
    else if (t < 16) ds[t - 8] = ei[N_EDGES + e0 + t - 8];
    __syncthreads();

    int g = t >> 5, o = t & 31;
    int src = ss[g], dst = ds[g];
    float acc = xb2[(size_t)src * 32 + o];
    const float4* grow = (const float4*)(G + (size_t)src * 1024 + o * 32);
#pragma unroll
    for (int j = 0; j < 8; ++j) {
        float4 v = grow[j];
        acc += hs[g * 32 + j * 4 + 0] * v.x;
        acc += hs[g * 32 + j * 4 + 1] * v.y;
        acc += hs[g * 32 + j * 4 + 2] * v.z;
        acc += hs[g * 32 + j * 4 + 3] * v.w;
    }
    atomicAdd(&aggout[(size_t)dst * 32 + o], acc);
}

// logits = relu(agg) @ fc_w + fc_b; out = log_softmax(logits)
__global__ __launch_bounds__(64) void k_final(const float* __restrict__ agg,
                                              const float* __restrict__ fcw,
                                              const float* __restrict__ fcb,
                                              float* __restrict__ out) {
    int n = blockIdx.x * 64 + threadIdx.x;
    if (n >= N_NODES) return;
    float l0 = fcb[0], l1 = fcb[1], l2 = fcb[2], l3 = fcb[3];
#pragma unroll
    for (int o = 0; o < 32; ++o) {
        float xv = agg[(size_t)n * 32 + o];
        xv = xv > 0.f ? xv : 0.f;
        l0 += xv * fcw[o * 4 + 0];
        l1 += xv * fcw[o * 4 + 1];
        l2 += xv * fcw[o * 4 + 2];
        l3 += xv * fcw[o * 4 + 3];
    }
    float m = fmaxf(fmaxf(l0, l1), fmaxf(l2, l3));
    float s = expf(l0 - m) + expf(l1 - m) + expf(l2 - m) + expf(l3 - m);
    float lse = m + logf(s);
    out[(size_t)n * 4 + 0] = l0 - lse;
    out[(size_t)n * 4 + 1] = l1 - lse;
    out[(size_t)n * 4 + 2] = l2 - lse;
    out[(size_t)n * 4 + 3] = l3 - lse;
}

extern "C" void kernel_launch(void* const* d_in, const int* in_sizes, int n_in,
                              void* d_out, int out_size, void* d_ws, size_t ws_size,
                              hipStream_t stream) {
    const float* x0 = (const float*)d_in[0];
    const int*   ei = (const int*)d_in[1];
    const float* ea = (const float*)d_in[2];
    const float *W1[3], *B1[3], *W2[3], *B2[3], *RT[3], *BS[3];
    for (int l = 0; l < 3; ++l) {
        W1[l] = (const float*)d_in[3 + 6 * l];
        B1[l] = (const float*)d_in[4 + 6 * l];
        W2[l] = (const float*)d_in[5 + 6 * l];
        B2[l] = (const float*)d_in[6 + 6 * l];
        RT[l] = (const float*)d_in[7 + 6 * l];
        BS[l] = (const float*)d_in[8 + 6 * l];
    }
    const float* fcw = (const float*)d_in[21];
    const float* fcb = (const float*)d_in[22];
    float* out = (float*)d_out;

    // workspace layout (fp32): aggA | aggB | xb2 | h [E,32] | G [N,1024]  (~65.3 MB)
    float* aggA = (float*)d_ws;
    float* aggB = aggA + (size_t)N_NODES * 32;
    float* xb2  = aggB + (size_t)N_NODES * 32;
    float* hbuf = xb2  + (size_t)N_NODES * 32;
    float* Gbuf = hbuf + (size_t)N_EDGES * 32;

    const int gh = N_EDGES * 32 / 256;  // 20000
    const int gG = N_NODES / 16;        // 625
    const int gS = N_NODES / 8;         // 1250
    const int gE = N_EDGES / 8;         // 20000

    // ---- layer 0: din=4, input x0, output aggA ----
    k_h<<<gh, 256, 0, stream>>>(ea, W1[0], B1[0], hbuf);
    k_G<4, true><<<gG, 256, 0, stream>>>(x0, W2[0], Gbuf);
    k_small<4, true><<<gS, 256, 0, stream>>>(x0, B2[0], RT[0], BS[0], xb2, aggA);
    k_edge<<<gE, 256, 0, stream>>>(ei, hbuf, Gbuf, xb2, aggA);

    // ---- layer 1: din=32, input relu(aggA), output aggB ----
    k_h<<<gh, 256, 0, stream>>>(ea, W1[1], B1[1], hbuf);
    k_G<32, false><<<gG, 256, 0, stream>>>(aggA, W2[1], Gbuf);
    k_small<32, false><<<gS, 256, 0, stream>>>(aggA, B2[1], RT[1], BS[1], xb2, aggB);
    k_edge<<<gE, 256, 0, stream>>>(ei, hbuf, Gbuf, xb2, aggB);

    // ---- layer 2: din=32, input relu(aggB), output aggA ----
    k_h<<<gh, 256, 0, stream>>>(ea, W1[2], B1[2], hbuf);
    k_G<32, false><<<gG, 256, 0, stream>>>(aggB, W2[2], Gbuf);
    k_small<32, false><<<gS, 256, 0, stream>>>(aggB, B2[2], RT[2], BS[2], xb2, aggA);
    k_edge<<<gE, 256, 0, stream>>>(ei, hbuf, Gbuf, xb2, aggA);

    // ---- head ----
    k_final<<<(N_NODES + 63) / 64, 64, 0, stream>>>(aggA, fcw, fcb, out);
}

// Round 2
// 350.300 us; speedup vs baseline: 1.4761x; 1.4761x over previous
//
#include <hip/hip_runtime.h>
#include <math.h>

#define N_NODES 10000
#define N_EDGES 160000

// ---------- counting sort of edges by src ----------
__global__ __launch_bounds__(256) void k_hist(const int* __restrict__ ei,
                                              int* __restrict__ cnt) {
    int e = blockIdx.x * 256 + threadIdx.x;
    if (e < N_EDGES) atomicAdd(&cnt[ei[e]], 1);
}

// single block: exclusive scan of cnt[10000] -> off[10001], cursor=off
__global__ __launch_bounds__(256) void k_scan(const int* __restrict__ cnt,
                                              int* __restrict__ off,
                                              int* __restrict__ cursor) {
    __shared__ int part[256];
    int t = threadIdx.x;
    int base = t * 40;                       // 250 threads cover 10000
    int s = 0;
    for (int i = 0; i < 40; ++i) {
        int idx = base + i;
        if (idx < N_NODES) s += cnt[idx];
    }
    part[t] = s;
    __syncthreads();
    for (int d = 1; d < 256; d <<= 1) {      // Hillis-Steele inclusive scan
        int v = (t >= d) ? part[t - d] : 0;
        __syncthreads();
        part[t] += v;
        __syncthreads();
    }
    int run = part[t] - s;                   // exclusive prefix
    for (int i = 0; i < 40; ++i) {
        int idx = base + i;
        if (idx < N_NODES) {
            off[idx] = run;
            cursor[idx] = run;
            run += cnt[idx];
        }
    }
    if (t == 255) off[N_NODES] = run;        // = N_EDGES
}

__global__ __launch_bounds__(256) void k_scatter(const int* __restrict__ ei,
                                                 const float* __restrict__ ea,
                                                 int* __restrict__ cursor,
                                                 int* __restrict__ dst_s,
                                                 float* __restrict__ ea_s) {
    int e = blockIdx.x * 256 + threadIdx.x;
    if (e >= N_EDGES) return;
    int src = ei[e], dst = ei[N_EDGES + e];
    int pos = atomicAdd(&cursor[src], 1);
    dst_s[pos] = dst;
    ea_s[2 * pos]     = ea[2 * e];
    ea_s[2 * pos + 1] = ea[2 * e + 1];
}

// ---------- transpose all three w2: w2t[i*1024 + o*32 + k] = w2[k*(din*32) + i*32 + o] ----------
__global__ __launch_bounds__(256) void k_tw2(const float* __restrict__ s0,
                                             const float* __restrict__ s1,
                                             const float* __restrict__ s2,
                                             float* __restrict__ t0,
                                             float* __restrict__ t1,
                                             float* __restrict__ t2) {
    int tid = blockIdx.x * 256 + threadIdx.x;
    if (tid < 4096) {                         // layer 0, din=4
        int i = tid >> 10, j = tid & 1023, o = j >> 5, k = j & 31;
        t0[tid] = s0[k * 128 + i * 32 + o];
    } else if (tid < 4096 + 32768) {
        int d = tid - 4096;
        int i = d >> 10, j = d & 1023, o = j >> 5, k = j & 31;
        t1[d] = s1[k * 1024 + i * 32 + o];
    } else if (tid < 4096 + 65536) {
        int d = tid - 4096 - 32768;
        int i = d >> 10, j = d & 1023, o = j >> 5, k = j & 31;
        t2[d] = s2[k * 1024 + i * 32 + o];
    }
}

// ---------- h in sorted edge order ----------
__global__ __launch_bounds__(256) void k_h(const float* __restrict__ ea_s,
                                           const float* __restrict__ w1,
                                           const float* __restrict__ b1,
                                           float* __restrict__ h_s) {
    int idx = blockIdx.x * 256 + threadIdx.x;  // idx = j*32 + k
    int j = idx >> 5, k = idx & 31;
    float v = ea_s[2 * j] * w1[k] + ea_s[2 * j + 1] * w1[32 + k] + b1[k];
    h_s[idx] = v > 0.f ? v : 0.f;
}

// ---------- G[n, o*32+k] = sum_i x[n,i]*w2t[i, o*32+k]; also xb2 and agg-init ----------
template <int DIN, bool FIRST>
__global__ __launch_bounds__(256) void k_G(const float* __restrict__ xin,
                                           const float* __restrict__ w2t,  // [DIN,1024]
                                           const float* __restrict__ b2,   // [DIN*32]
                                           const float* __restrict__ root, // [DIN,32]
                                           const float* __restrict__ bias, // [32]
                                           float* __restrict__ G,
                                           float* __restrict__ xb2,
                                           float* __restrict__ agg) {
    const int t = threadIdx.x;
    const int n0 = blockIdx.x * 16;

    __shared__ float xs[16 * DIN];
    for (int idx = t; idx < 16 * DIN; idx += 256) {
        int m = idx / DIN, i = idx - m * DIN;
        float v = xin[(size_t)(n0 + m) * DIN + i];
        if (!FIRST) v = v > 0.f ? v : 0.f;
        xs[idx] = v;
    }
    __syncthreads();

    float acc[16][4];
#pragma unroll
    for (int m = 0; m < 16; ++m)
        acc[m][0] = acc[m][1] = acc[m][2] = acc[m][3] = 0.f;

#pragma unroll
    for (int i = 0; i < DIN; ++i) {
        const float4 w = *(const float4*)(w2t + i * 1024 + t * 4);
#pragma unroll
        for (int m = 0; m < 16; ++m) {
            float xv = xs[m * DIN + i];
            acc[m][0] += xv * w.x;
            acc[m][1] += xv * w.y;
            acc[m][2] += xv * w.z;
            acc[m][3] += xv * w.w;
        }
    }
#pragma unroll
    for (int m = 0; m < 16; ++m)
        *(float4*)(G + (size_t)(n0 + m) * 1024 + t * 4) =
            make_float4(acc[m][0], acc[m][1], acc[m][2], acc[m][3]);

    // xb2[n,o] and agg[n,o] = bias + x@root  (512 outputs, 2 per thread)
    for (int idx = t; idx < 512; idx += 256) {
        int m = idx >> 5, o = idx & 31;
        float ab = 0.f, ar = bias[o];
#pragma unroll
        for (int i = 0; i < DIN; ++i) {
            float xv = xs[m * DIN + i];
            ab += xv * b2[i * 32 + o];
            ar += xv * root[i * 32 + o];
        }
        size_t p = (size_t)(n0 + m) * 32 + o;
        xb2[p] = ab;
        agg[p] = ar;
    }
}

// ---------- per-node edge processing: G row in regs, stream sorted edge list ----------
__global__ __launch_bounds__(256) void k_edge(const int* __restrict__ off,
                                              const int* __restrict__ dst_s,
                                              const float* __restrict__ h_s,
                                              const float* __restrict__ G,
                                              const float* __restrict__ xb2,
                                              float* __restrict__ agg) {
    int t = threadIdx.x;
    int n = blockIdx.x * 8 + (t >> 5);       // 8 nodes per block, 10000 exact
    int o = t & 31;

    const float4* gp = (const float4*)(G + (size_t)n * 1024 + o * 32);
    float4 g0 = gp[0], g1 = gp[1], g2 = gp[2], g3 = gp[3];
    float4 g4 = gp[4], g5 = gp[5], g6 = gp[6], g7 = gp[7];
    float xb = xb2[(size_t)n * 32 + o];
    int jb = off[n], je = off[n + 1];

    for (int j = jb; j < je; ++j) {
        const float4* hp = (const float4*)(h_s + (size_t)j * 32);
        float acc = xb;
        float4 h0 = hp[0]; acc += h0.x * g0.x + h0.y * g0.y + h0.z * g0.z + h0.w * g0.w;
        float4 h1 = hp[1]; acc += h1.x * g1.x + h1.y * g1.y + h1.z * g1.z + h1.w * g1.w;
        float4 h2 = hp[2]; acc += h2.x * g2.x + h2.y * g2.y + h2.z * g2.z + h2.w * g2.w;
        float4 h3 = hp[3]; acc += h3.x * g3.x + h3.y * g3.y + h3.z * g3.z + h3.w * g3.w;
        float4 h4 = hp[4]; acc += h4.x * g4.x + h4.y * g4.y + h4.z * g4.z + h4.w * g4.w;
        float4 h5 = hp[5]; acc += h5.x * g5.x + h5.y * g5.y + h5.z * g5.z + h5.w * g5.w;
        float4 h6 = hp[6]; acc += h6.x * g6.x + h6.y * g6.y + h6.z * g6.z + h6.w * g6.w;
        float4 h7 = hp[7]; acc += h7.x * g7.x + h7.y * g7.y + h7.z * g7.z + h7.w * g7.w;
        int d = dst_s[j];
        atomicAdd(&agg[(size_t)d * 32 + o], acc);
    }
}

// ---------- head ----------
__global__ __launch_bounds__(64) void k_final(const float* __restrict__ agg,
                                              const float* __restrict__ fcw,
                                              const float* __restrict__ fcb,
                                              float* __restrict__ out) {
    int n = blockIdx.x * 64 + threadIdx.x;
    if (n >= N_NODES) return;
    float l0 = fcb[0], l1 = fcb[1], l2 = fcb[2], l3 = fcb[3];
#pragma unroll
    for (int o = 0; o < 32; ++o) {
        float xv = agg[(size_t)n * 32 + o];
        xv = xv > 0.f ? xv : 0.f;
        l0 += xv * fcw[o * 4 + 0];
        l1 += xv * fcw[o * 4 + 1];
        l2 += xv * fcw[o * 4 + 2];
        l3 += xv * fcw[o * 4 + 3];
    }
    float m = fmaxf(fmaxf(l0, l1), fmaxf(l2, l3));
    float s = expf(l0 - m) + expf(l1 - m) + expf(l2 - m) + expf(l3 - m);
    float lse = m + logf(s);
    out[(size_t)n * 4 + 0] = l0 - lse;
    out[(size_t)n * 4 + 1] = l1 - lse;
    out[(size_t)n * 4 + 2] = l2 - lse;
    out[(size_t)n * 4 + 3] = l3 - lse;
}

extern "C" void kernel_launch(void* const* d_in, const int* in_sizes, int n_in,
                              void* d_out, int out_size, void* d_ws, size_t ws_size,
                              hipStream_t stream) {
    const float* x0 = (const float*)d_in[0];
    const int*   ei = (const int*)d_in[1];
    const float* ea = (const float*)d_in[2];
    const float *W1[3], *B1[3], *W2[3], *B2[3], *RT[3], *BS[3];
    for (int l = 0; l < 3; ++l) {
        W1[l] = (const float*)d_in[3 + 6 * l];
        B1[l] = (const float*)d_in[4 + 6 * l];
        W2[l] = (const float*)d_in[5 + 6 * l];
        B2[l] = (const float*)d_in[6 + 6 * l];
        RT[l] = (const float*)d_in[7 + 6 * l];
        BS[l] = (const float*)d_in[8 + 6 * l];
    }
    const float* fcw = (const float*)d_in[21];
    const float* fcb = (const float*)d_in[22];
    float* out = (float*)d_out;

    // ---- workspace layout (16B-aligned segments) ----
    int*   cnt    = (int*)d_ws;             // 10240
    int*   cursor = cnt + 10240;            // 10240
    int*   off    = cursor + 10240;         // 10240 (uses 10001)
    int*   dst_s  = off + 10240;            // 160000
    float* ea_s   = (float*)(dst_s + 160000);        // 320000
    float* h_s    = ea_s + 320000;                   // 5,120,000
    float* G      = h_s + 5120000;                   // 10,240,000
    float* xb2    = G + 10240000;                    // 320000
    float* aggA   = xb2 + 320000;                    // 320000
    float* aggB   = aggA + 320000;                   // 320000
    float* w2t0   = aggB + 320000;                   // 4096
    float* w2t1   = w2t0 + 4096;                     // 32768
    float* w2t2   = w2t1 + 32768;                    // 32768

    const int gE256 = (N_EDGES + 255) / 256;   // 625
    const int gH    = N_EDGES * 32 / 256;      // 20000
    const int gG    = N_NODES / 16;            // 625
    const int gEdge = N_NODES / 8;             // 1250

    // ---- sort edges by src (once, reused by all layers) ----
    hipMemsetAsync(cnt, 0, N_NODES * sizeof(int), stream);
    k_hist<<<gE256, 256, 0, stream>>>(ei, cnt);
    k_scan<<<1, 256, 0, stream>>>(cnt, off, cursor);
    k_scatter<<<gE256, 256, 0, stream>>>(ei, ea, cursor, dst_s, ea_s);
    k_tw2<<<(4096 + 65536 + 255) / 256, 256, 0, stream>>>(W2[0], W2[1], W2[2], w2t0, w2t1, w2t2);

    // ---- layer 0 (din=4) ----
    k_h<<<gH, 256, 0, stream>>>(ea_s, W1[0], B1[0], h_s);
    k_G<4, true><<<gG, 256, 0, stream>>>(x0, w2t0, B2[0], RT[0], BS[0], G, xb2, aggA);
    k_edge<<<gEdge, 256, 0, stream>>>(off, dst_s, h_s, G, xb2, aggA);

    // ---- layer 1 (din=32) ----
    k_h<<<gH, 256, 0, stream>>>(ea_s, W1[1], B1[1], h_s);
    k_G<32, false><<<gG, 256, 0, stream>>>(aggA, w2t1, B2[1], RT[1], BS[1], G, xb2, aggB);
    k_edge<<<gEdge, 256, 0, stream>>>(off, dst_s, h_s, G, xb2, aggB);

    // ---- layer 2 (din=32) ----
    k_h<<<gH, 256, 0, stream>>>(ea_s, W1[2], B1[2], h_s);
    k_G<32, false><<<gG, 256, 0, stream>>>(aggB, w2t2, B2[2], RT[2], BS[2], G, xb2, aggA);
    k_edge<<<gEdge, 256, 0, stream>>>(off, dst_s, h_s, G, xb2, aggA);

    // ---- head ----
    k_final<<<(N_NODES + 63) / 64, 64, 0, stream>>>(aggA, fcw, fcb, out);
}

// Round 3
// 278.840 us; speedup vs baseline: 1.8544x; 1.2563x over previous
//
#include <hip/hip_runtime.h>
#include <hip/hip_bf16.h>
#include <math.h>

#define N_NODES 10000
#define N_EDGES 160000

typedef __attribute__((ext_vector_type(8))) short bf16x8;
typedef __attribute__((ext_vector_type(4))) float f32x4;

static __device__ inline unsigned short f2b(float v) {
    __hip_bfloat16 b = __float2bfloat16(v);
    return *reinterpret_cast<unsigned short*>(&b);
}

// ---------- zero cnt + transpose all three w2 ----------
// w2t[i*1024 + o*32 + k] = w2[k*(din*32) + i*32 + o]
__global__ __launch_bounds__(256) void k_tw2z(const float* __restrict__ s0,
                                              const float* __restrict__ s1,
                                              const float* __restrict__ s2,
                                              float* __restrict__ t0,
                                              float* __restrict__ t1,
                                              float* __restrict__ t2,
                                              int* __restrict__ cnt) {
    int tid = blockIdx.x * 256 + threadIdx.x;
    if (tid < 10240) { cnt[tid] = 0; return; }
    int d = tid - 10240;
    if (d < 4096) {                            // layer 0, din=4
        int i = d >> 10, j = d & 1023, o = j >> 5, k = j & 31;
        t0[d] = s0[k * 128 + i * 32 + o];
    } else if (d < 4096 + 32768) {
        int q = d - 4096;
        int i = q >> 10, j = q & 1023, o = j >> 5, k = j & 31;
        t1[q] = s1[k * 1024 + i * 32 + o];
    } else if (d < 4096 + 65536) {
        int q = d - 4096 - 32768;
        int i = q >> 10, j = q & 1023, o = j >> 5, k = j & 31;
        t2[q] = s2[k * 1024 + i * 32 + o];
    }
}

// ---------- counting sort by src: hist ----------
__global__ __launch_bounds__(256) void k_hist(const int* __restrict__ ei,
                                              int* __restrict__ cnt) {
    int e = blockIdx.x * 256 + threadIdx.x;
    if (e < N_EDGES) atomicAdd(&cnt[ei[e]], 1);
}

// single block: exclusive scan of cnt[10000] -> off[10001], cursor=off
__global__ __launch_bounds__(256) void k_scan(const int* __restrict__ cnt,
                                              int* __restrict__ off,
                                              int* __restrict__ cursor) {
    __shared__ int part[256];
    int t = threadIdx.x;
    int base = t * 40;
    int s = 0;
    for (int i = 0; i < 40; ++i) {
        int idx = base + i;
        if (idx < N_NODES) s += cnt[idx];
    }
    part[t] = s;
    __syncthreads();
    for (int d = 1; d < 256; d <<= 1) {
        int v = (t >= d) ? part[t - d] : 0;
        __syncthreads();
        part[t] += v;
        __syncthreads();
    }
    int run = part[t] - s;
    for (int i = 0; i < 40; ++i) {
        int idx = base + i;
        if (idx < N_NODES) {
            off[idx] = run;
            cursor[idx] = run;
            run += cnt[idx];
        }
    }
    if (t == 255) off[N_NODES] = run;
}

// ---------- scatter edges into src-sorted order + compute h (all 3 layers, bf16) ----------
__global__ __launch_bounds__(256) void k_scatter_h(const int* __restrict__ ei,
                                                   const float* __restrict__ ea,
                                                   int* __restrict__ cursor,
                                                   int* __restrict__ dst_s,
                                                   const float* __restrict__ w1a, const float* __restrict__ b1a,
                                                   const float* __restrict__ w1b, const float* __restrict__ b1b,
                                                   const float* __restrict__ w1c, const float* __restrict__ b1c,
                                                   unsigned short* __restrict__ h0,
                                                   unsigned short* __restrict__ h1,
                                                   unsigned short* __restrict__ h2) {
    int e = blockIdx.x * 256 + threadIdx.x;
    if (e >= N_EDGES) return;
    float a0 = ea[2 * e], a1 = ea[2 * e + 1];
    int src = ei[e], dst = ei[N_EDGES + e];
    int pos = atomicAdd(&cursor[src], 1);
    dst_s[pos] = dst;
    const float* W1[3] = {w1a, w1b, w1c};
    const float* B1[3] = {b1a, b1b, b1c};
    unsigned short* H[3] = {h0, h1, h2};
#pragma unroll
    for (int l = 0; l < 3; ++l) {
        unsigned int pk[16];
#pragma unroll
        for (int j = 0; j < 16; ++j) {
            float v0 = fmaxf(a0 * W1[l][2 * j]     + a1 * W1[l][32 + 2 * j]     + B1[l][2 * j],     0.f);
            float v1 = fmaxf(a0 * W1[l][2 * j + 1] + a1 * W1[l][32 + 2 * j + 1] + B1[l][2 * j + 1], 0.f);
            pk[j] = (unsigned int)f2b(v0) | ((unsigned int)f2b(v1) << 16);
        }
        uint4* dp = (uint4*)(H[l] + (size_t)pos * 32);
        dp[0] = make_uint4(pk[0], pk[1], pk[2], pk[3]);
        dp[1] = make_uint4(pk[4], pk[5], pk[6], pk[7]);
        dp[2] = make_uint4(pk[8], pk[9], pk[10], pk[11]);
        dp[3] = make_uint4(pk[12], pk[13], pk[14], pk[15]);
    }
}

// ---------- G[n, o*32+k] (bf16) = sum_i x[n,i]*w2t[i, o*32+k]; also xb2, agg-init (fp32) ----------
template <int DIN, bool FIRST>
__global__ __launch_bounds__(256) void k_G(const float* __restrict__ xin,
                                           const float* __restrict__ w2t,  // [DIN,1024]
                                           const float* __restrict__ b2,   // [DIN*32]
                                           const float* __restrict__ root, // [DIN,32]
                                           const float* __restrict__ bias, // [32]
                                           unsigned short* __restrict__ Gb,
                                           float* __restrict__ xb2,
                                           float* __restrict__ agg) {
    const int t = threadIdx.x;
    const int n0 = blockIdx.x * 16;

    __shared__ float xs[16 * DIN];
    for (int idx = t; idx < 16 * DIN; idx += 256) {
        int m = idx / DIN, i = idx - m * DIN;
        float v = xin[(size_t)(n0 + m) * DIN + i];
        if (!FIRST) v = v > 0.f ? v : 0.f;
        xs[idx] = v;
    }
    __syncthreads();

    float acc[16][4];
#pragma unroll
    for (int m = 0; m < 16; ++m)
        acc[m][0] = acc[m][1] = acc[m][2] = acc[m][3] = 0.f;

#pragma unroll
    for (int i = 0; i < DIN; ++i) {
        const float4 w = *(const float4*)(w2t + i * 1024 + t * 4);
#pragma unroll
        for (int m = 0; m < 16; ++m) {
            float xv = xs[m * DIN + i];
            acc[m][0] += xv * w.x;
            acc[m][1] += xv * w.y;
            acc[m][2] += xv * w.z;
            acc[m][3] += xv * w.w;
        }
    }
#pragma unroll
    for (int m = 0; m < 16; ++m) {
        unsigned int p0 = (unsigned int)f2b(acc[m][0]) | ((unsigned int)f2b(acc[m][1]) << 16);
        unsigned int p1 = (unsigned int)f2b(acc[m][2]) | ((unsigned int)f2b(acc[m][3]) << 16);
        *(uint2*)(Gb + (size_t)(n0 + m) * 1024 + t * 4) = make_uint2(p0, p1);
    }

    for (int idx = t; idx < 512; idx += 256) {
        int m = idx >> 5, o = idx & 31;
        float ab = 0.f, ar = bias[o];
#pragma unroll
        for (int i = 0; i < DIN; ++i) {
            float xv = xs[m * DIN + i];
            ab += xv * b2[i * 32 + o];
            ar += xv * root[i * 32 + o];
        }
        size_t p = (size_t)(n0 + m) * 32 + o;
        xb2[p] = ab;
        agg[p] = ar;
    }
}

// ---------- MFMA edge kernel: one wave per node ----------
// msg[E_tile(16) x 32] = H_tile(16x32) @ G_n^T, acc init = xb2 broadcast, atomic scatter by dst
__global__ __launch_bounds__(256) void k_edge(const int* __restrict__ off,
                                              const int* __restrict__ dst_s,
                                              const unsigned short* __restrict__ hb,
                                              const unsigned short* __restrict__ Gb,
                                              const float* __restrict__ xb2,
                                              float* __restrict__ agg) {
    int t = threadIdx.x;
    int lane = t & 63;
    int n = blockIdx.x * 4 + (t >> 6);
    int col = lane & 15;     // C col = o (low half); A row m = edge-in-tile
    int quad = lane >> 4;    // k-block selector

    // B frags: B[k=quad*8+j][o=col] = G_n[o*32 + k]
    const bf16x8 b_lo = *(const bf16x8*)(Gb + (size_t)n * 1024 + col * 32 + quad * 8);
    const bf16x8 b_hi = *(const bf16x8*)(Gb + (size_t)n * 1024 + (col + 16) * 32 + quad * 8);
    float xb_lo = xb2[(size_t)n * 32 + col];
    float xb_hi = xb2[(size_t)n * 32 + 16 + col];

    int jb = off[n], je = off[n + 1];
    for (int e0 = jb; e0 < je; e0 += 16) {
        int eA = e0 + col;
        bf16x8 afrag = {0, 0, 0, 0, 0, 0, 0, 0};
        if (eA < je) afrag = *(const bf16x8*)(hb + (size_t)eA * 32 + quad * 8);
        f32x4 acc_lo = {xb_lo, xb_lo, xb_lo, xb_lo};
        f32x4 acc_hi = {xb_hi, xb_hi, xb_hi, xb_hi};
        acc_lo = __builtin_amdgcn_mfma_f32_16x16x32_bf16(afrag, b_lo, acc_lo, 0, 0, 0);
        acc_hi = __builtin_amdgcn_mfma_f32_16x16x32_bf16(afrag, b_hi, acc_hi, 0, 0, 0);
#pragma unroll
        for (int r = 0; r < 4; ++r) {
            int er = e0 + quad * 4 + r;       // C row = edge-in-tile
            if (er < je) {
                int d = dst_s[er];
                atomicAdd(&agg[(size_t)d * 32 + col], acc_lo[r]);
                atomicAdd(&agg[(size_t)d * 32 + 16 + col], acc_hi[r]);
            }
        }
    }
}

// ---------- head ----------
__global__ __launch_bounds__(64) void k_final(const float* __restrict__ agg,
                                              const float* __restrict__ fcw,
                                              const float* __restrict__ fcb,
                                              float* __restrict__ out) {
    int n = blockIdx.x * 64 + threadIdx.x;
    if (n >= N_NODES) return;
    float l0 = fcb[0], l1 = fcb[1], l2 = fcb[2], l3 = fcb[3];
#pragma unroll
    for (int o = 0; o < 32; ++o) {
        float xv = agg[(size_t)n * 32 + o];
        xv = xv > 0.f ? xv : 0.f;
        l0 += xv * fcw[o * 4 + 0];
        l1 += xv * fcw[o * 4 + 1];
        l2 += xv * fcw[o * 4 + 2];
        l3 += xv * fcw[o * 4 + 3];
    }
    float m = fmaxf(fmaxf(l0, l1), fmaxf(l2, l3));
    float s = expf(l0 - m) + expf(l1 - m) + expf(l2 - m) + expf(l3 - m);
    float lse = m + logf(s);
    out[(size_t)n * 4 + 0] = l0 - lse;
    out[(size_t)n * 4 + 1] = l1 - lse;
    out[(size_t)n * 4 + 2] = l2 - lse;
    out[(size_t)n * 4 + 3] = l3 - lse;
}

extern "C" void kernel_launch(void* const* d_in, const int* in_sizes, int n_in,
                              void* d_out, int out_size, void* d_ws, size_t ws_size,
                              hipStream_t stream) {
    const float* x0 = (const float*)d_in[0];
    const int*   ei = (const int*)d_in[1];
    const float* ea = (const float*)d_in[2];
    const float *W1[3], *B1[3], *W2[3], *B2[3], *RT[3], *BS[3];
    for (int l = 0; l < 3; ++l) {
        W1[l] = (const float*)d_in[3 + 6 * l];
        B1[l] = (const float*)d_in[4 + 6 * l];
        W2[l] = (const float*)d_in[5 + 6 * l];
        B2[l] = (const float*)d_in[6 + 6 * l];
        RT[l] = (const float*)d_in[7 + 6 * l];
        BS[l] = (const float*)d_in[8 + 6 * l];
    }
    const float* fcw = (const float*)d_in[21];
    const float* fcb = (const float*)d_in[22];
    float* out = (float*)d_out;

    // ---- workspace layout (all segment starts 16B-aligned) ----
    int*   cnt    = (int*)d_ws;                       // 10240
    int*   cursor = cnt + 10240;                      // 10240
    int*   off    = cursor + 10240;                   // 10240 (10001 used)
    int*   dst_s  = off + 10240;                      // 160000
    float* w2t0   = (float*)(dst_s + 160000);         // 4096
    float* w2t1   = w2t0 + 4096;                      // 32768
    float* w2t2   = w2t1 + 32768;                     // 32768
    float* xb2    = w2t2 + 32768;                     // 320000
    float* aggA   = xb2 + 320000;                     // 320000
    float* aggB   = aggA + 320000;                    // 320000
    unsigned short* h0 = (unsigned short*)(aggB + 320000);  // 5,120,000
    unsigned short* h1 = h0 + 5120000;                      // 5,120,000
    unsigned short* h2 = h1 + 5120000;                      // 5,120,000
    unsigned short* Gb = h2 + 5120000;                      // 10,240,000

    const int gE256 = (N_EDGES + 255) / 256;   // 625
    const int gG    = N_NODES / 16;            // 625
    const int gEdge = N_NODES / 4;             // 2500 (1 wave per node, 4 waves/block)

    // ---- once-per-call preprocessing ----
    k_tw2z<<<312, 256, 0, stream>>>(W2[0], W2[1], W2[2], w2t0, w2t1, w2t2, cnt);
    k_hist<<<gE256, 256, 0, stream>>>(ei, cnt);
    k_scan<<<1, 256, 0, stream>>>(cnt, off, cursor);
    k_scatter_h<<<gE256, 256, 0, stream>>>(ei, ea, cursor, dst_s,
                                           W1[0], B1[0], W1[1], B1[1], W1[2], B1[2],
                                           h0, h1, h2);

    // ---- layer 0 (din=4) ----
    k_G<4, true><<<gG, 256, 0, stream>>>(x0, w2t0, B2[0], RT[0], BS[0], Gb, xb2, aggA);
    k_edge<<<gEdge, 256, 0, stream>>>(off, dst_s, h0, Gb, xb2, aggA);

    // ---- layer 1 (din=32) ----
    k_G<32, false><<<gG, 256, 0, stream>>>(aggA, w2t1, B2[1], RT[1], BS[1], Gb, xb2, aggB);
    k_edge<<<gEdge, 256, 0, stream>>>(off, dst_s, h1, Gb, xb2, aggB);

    // ---- layer 2 (din=32) ----
    k_G<32, false><<<gG, 256, 0, stream>>>(aggB, w2t2, B2[2], RT[2], BS[2], Gb, xb2, aggA);
    k_edge<<<gEdge, 256, 0, stream>>>(off, dst_s, h2, Gb, xb2, aggA);

    // ---- head ----
    k_final<<<(N_NODES + 63) / 64, 64, 0, stream>>>(aggA, fcw, fcb, out);
}